// Round 6
// baseline (679.727 us; speedup 1.0000x reference)
//
#include <hip/hip_runtime.h>

// SimpleAttention v6: TT=16, 512-thr blocks, 64KB p-LDS -> 2 blocks/CU
// (phase-staggered), wave-broadcast ctx loads, k+1 ctx prefetch.
// out[b, i*64+d, t] = sum_j softmax_j(a[i][j]) * ctx[j][d]   (per b,t)
// attentions[b,i,j,t] = p[j] + (i==j ? 0 : p[j+32])

typedef unsigned int uint_t;

constexpr int Bq = 16, Cq = 3072, Tq = 2048;
constexpr int TT = 16;                   // t-tile
constexpr int TILES = Tq / TT;           // 128
constexpr int NBLK = Bq * TILES;         // 2048
constexpr size_t ATT_OFF = (size_t)Bq * 2048 * Tq;

__global__ __launch_bounds__(512, 4) void attn_v6(const float* __restrict__ x,
                                                  const float* __restrict__ xi,
                                                  float* __restrict__ out)
{
    // p packed bf16 pairs: word k holds (p[2k],p[2k+1]) for row i, time tl.
    // word-index = k*512 + tl*32 + (i ^ ((tl&7)<<2))  -> 64 KB
    __shared__ uint_t plds[32 * 16 * 32];

    // XCD swizzle: logical tiles 2m,2m+1 (sharing 128B lines) land on same XCD
    const unsigned lin = blockIdx.x;
    const unsigned swz = (lin & 7u) * (NBLK / 8) + (lin >> 3);
    const int b    = (int)(swz >> 7);            // / TILES
    const int tile = (int)(swz & (TILES - 1));
    const int t0   = tile * TT;
    const int tl   = (int)threadIdx.x & 15;
    const int slot = (int)threadIdx.x >> 4;      // 0..31
    const int xw   = (tl & 7) << 2;              // word-index XOR swizzle

    const float* xb  = x  + (size_t)b * Cq * Tq + t0 + tl;
    const float* xib = xi + (size_t)b * Cq * Tq + t0 + tl;

    // ---- phase A: softmax for row i = slot; attn out; p -> LDS ----
    {
        const int i = slot;
        float p[64];
#pragma unroll
        for (int j = 0; j < 32; ++j) p[j]      = xb [(size_t)(i * 96 + j) * Tq];
#pragma unroll
        for (int j = 0; j < 32; ++j) p[j + 32] = xib[(size_t)(i * 96 + j) * Tq];
        float m = p[0];
#pragma unroll
        for (int j = 1; j < 64; ++j) m = fmaxf(m, p[j]);
        float s = 0.f;
#pragma unroll
        for (int j = 0; j < 64; ++j) { p[j] = __expf(p[j] - m); s += p[j]; }
        const float inv = 1.f / s;
#pragma unroll
        for (int j = 0; j < 64; ++j) p[j] *= inv;

        float* ao = out + ATT_OFF + ((size_t)(b * 32 + i) * 32) * Tq + t0 + tl;
#pragma unroll
        for (int j = 0; j < 32; ++j) {
            float v = p[j] + ((j == i) ? 0.f : p[j + 32]);
            __builtin_nontemporal_store(v, &ao[(size_t)j * Tq]);
        }
#pragma unroll
        for (int k = 0; k < 32; ++k) {
            uint_t b0 = __float_as_uint(p[2 * k]);
            uint_t b1 = __float_as_uint(p[2 * k + 1]);
            uint_t lo = (b0 + 0x7fffu + ((b0 >> 16) & 1u)) >> 16;
            uint_t hi = (b1 + 0x7fffu + ((b1 >> 16) & 1u)) >> 16;
            plds[k * 512 + tl * 32 + (i ^ xw)] = lo | (hi << 16);
        }
    }

    // ---- phase B: thread = (ig,dg,tl); acc 8i x 8d ----
    const int ig = slot & 3;                     // i = ig*8 + r
    const int dg = slot >> 2;                    // d = dg*8 + dd  (all 4 ig of a wave share dg)
    const int d0 = dg * 8;
    const int pbase = tl * 32;

    const float* cx  = x  + (size_t)b * Cq * Tq + (size_t)(32 + d0) * Tq + t0 + tl;
    const float* cxi = xi + (size_t)b * Cq * Tq + (size_t)(32 + d0) * Tq + t0 + tl;

    float acc[8][8];
#pragma unroll
    for (int r = 0; r < 8; ++r)
#pragma unroll
        for (int dd = 0; dd < 8; ++dd) acc[r][dd] = 0.f;

    // issue k=0 ctx loads before the barrier (independent of LDS)
    float c0[8], c1[8];
#pragma unroll
    for (int dd = 0; dd < 8; ++dd) c0[dd] = cx[(size_t)dd * Tq];
#pragma unroll
    for (int dd = 0; dd < 8; ++dd) c1[dd] = cx[(size_t)(96 + dd) * Tq];

    __syncthreads();

    // j-pairs: k = 0..15 from x (j=2k,2k+1), k = 16..31 from xi
#pragma unroll 2
    for (int k = 0; k < 32; ++k) {
        // prefetch next iteration's ctx while this iteration's FMAs run
        float n0[8], n1[8];
        if (k < 31) {
            const float* nb = ((k + 1) < 16) ? cx : cxi;
            const int ng = (k + 1) & 15;
#pragma unroll
            for (int dd = 0; dd < 8; ++dd)
                n0[dd] = nb[(size_t)(ng * 192 + dd) * Tq];
#pragma unroll
            for (int dd = 0; dd < 8; ++dd)
                n1[dd] = nb[(size_t)(ng * 192 + 96 + dd) * Tq];
        }

        const uint4 wa = *reinterpret_cast<const uint4*>(
            &plds[k * 512 + pbase + ((ig * 8 + 0) ^ xw)]);
        const uint4 wb = *reinterpret_cast<const uint4*>(
            &plds[k * 512 + pbase + ((ig * 8 + 4) ^ xw)]);
        float pj0[8], pj1[8];
        pj0[0] = __uint_as_float(wa.x << 16);  pj1[0] = __uint_as_float(wa.x & 0xffff0000u);
        pj0[1] = __uint_as_float(wa.y << 16);  pj1[1] = __uint_as_float(wa.y & 0xffff0000u);
        pj0[2] = __uint_as_float(wa.z << 16);  pj1[2] = __uint_as_float(wa.z & 0xffff0000u);
        pj0[3] = __uint_as_float(wa.w << 16);  pj1[3] = __uint_as_float(wa.w & 0xffff0000u);
        pj0[4] = __uint_as_float(wb.x << 16);  pj1[4] = __uint_as_float(wb.x & 0xffff0000u);
        pj0[5] = __uint_as_float(wb.y << 16);  pj1[5] = __uint_as_float(wb.y & 0xffff0000u);
        pj0[6] = __uint_as_float(wb.z << 16);  pj1[6] = __uint_as_float(wb.z & 0xffff0000u);
        pj0[7] = __uint_as_float(wb.w << 16);  pj1[7] = __uint_as_float(wb.w & 0xffff0000u);

#pragma unroll
        for (int r = 0; r < 8; ++r)
#pragma unroll
            for (int dd = 0; dd < 8; ++dd)
                acc[r][dd] += pj0[r] * c0[dd] + pj1[r] * c1[dd];

        if (k < 31) {
#pragma unroll
            for (int dd = 0; dd < 8; ++dd) { c0[dd] = n0[dd]; c1[dd] = n1[dd]; }
        }
    }

    float* ob = out + (size_t)b * 2048 * Tq + t0 + tl;
#pragma unroll
    for (int r = 0; r < 8; ++r)
#pragma unroll
        for (int dd = 0; dd < 8; ++dd) {
            int ch = (ig * 8 + r) * 64 + d0 + dd;
            __builtin_nontemporal_store(acc[r][dd], &ob[(size_t)ch * Tq]);
        }
}

extern "C" void kernel_launch(void* const* d_in, const int* in_sizes, int n_in,
                              void* d_out, int out_size, void* d_ws, size_t ws_size,
                              hipStream_t stream) {
    const float* x  = (const float*)d_in[0];
    const float* xi = (const float*)d_in[1];
    float* out = (float*)d_out;
    attn_v6<<<dim3(NBLK), dim3(512), 0, stream>>>(x, xi, out);
}

// Round 7
// 367.288 us; speedup vs baseline: 1.8507x; 1.8507x over previous
//
#include <hip/hip_runtime.h>

// SimpleAttention v7: v5 phase-B body verbatim; TT=16, 512-thr blocks,
// 64KB p-LDS -> 2 blocks/CU phase-staggered. No in-loop prefetch (v6 spilled).
// out[b, i*64+d, t] = sum_j softmax_j(a[i][j]) * ctx[j][d]   (per b,t)
// attentions[b,i,j,t] = p[j] + (i==j ? 0 : p[j+32])

typedef unsigned int uint_t;

constexpr int Bq = 16, Cq = 3072, Tq = 2048;
constexpr int TT = 16;                   // t-tile
constexpr int TILES = Tq / TT;           // 128
constexpr int NBLK = Bq * TILES;         // 2048
constexpr size_t ATT_OFF = (size_t)Bq * 2048 * Tq;

__global__ __launch_bounds__(512, 4) void attn_v7(const float* __restrict__ x,
                                                  const float* __restrict__ xi,
                                                  float* __restrict__ out)
{
    // p packed bf16 pairs: word k holds (p[2k],p[2k+1]) for row i, time tl.
    // word-index = k*512 + tl*32 + (i ^ ((tl&7)<<2))  -> 64 KB
    __shared__ uint_t plds[32 * 16 * 32];

    // XCD swizzle: tiles 2m,2m+1 (t-halves of the same 128B lines) -> same XCD
    const unsigned lin = blockIdx.x;
    const unsigned swz = (lin & 7u) * (NBLK / 8) + (lin >> 3);
    const int b    = (int)(swz >> 7);            // / TILES
    const int tile = (int)(swz & (TILES - 1));
    const int t0   = tile * TT;
    const int tl   = (int)threadIdx.x & 15;
    const int slot = (int)threadIdx.x >> 4;      // 0..31
    const int xw   = (tl & 7) << 2;              // word-index XOR swizzle

    const float* xb  = x  + (size_t)b * Cq * Tq + t0 + tl;
    const float* xib = xi + (size_t)b * Cq * Tq + t0 + tl;

    // ---- phase A: softmax for row i = slot; attn out; p -> LDS ----
    {
        const int i = slot;
        float p[64];
#pragma unroll
        for (int j = 0; j < 32; ++j) p[j]      = xb [(size_t)(i * 96 + j) * Tq];
#pragma unroll
        for (int j = 0; j < 32; ++j) p[j + 32] = xib[(size_t)(i * 96 + j) * Tq];
        float m = p[0];
#pragma unroll
        for (int j = 1; j < 64; ++j) m = fmaxf(m, p[j]);
        float s = 0.f;
#pragma unroll
        for (int j = 0; j < 64; ++j) { p[j] = __expf(p[j] - m); s += p[j]; }
        const float inv = 1.f / s;
#pragma unroll
        for (int j = 0; j < 64; ++j) p[j] *= inv;

        float* ao = out + ATT_OFF + ((size_t)(b * 32 + i) * 32) * Tq + t0 + tl;
#pragma unroll
        for (int j = 0; j < 32; ++j) {
            float v = p[j] + ((j == i) ? 0.f : p[j + 32]);
            __builtin_nontemporal_store(v, &ao[(size_t)j * Tq]);
        }
#pragma unroll
        for (int k = 0; k < 32; ++k) {
            uint_t b0 = __float_as_uint(p[2 * k]);
            uint_t b1 = __float_as_uint(p[2 * k + 1]);
            uint_t lo = (b0 + 0x7fffu + ((b0 >> 16) & 1u)) >> 16;
            uint_t hi = (b1 + 0x7fffu + ((b1 >> 16) & 1u)) >> 16;
            plds[k * 512 + tl * 32 + (i ^ xw)] = lo | (hi << 16);
        }
    }

    // ---- phase B: thread = (ig,dg,tl); acc 8i x 8d; v5 body verbatim ----
    const int ig = slot & 3;                     // i = ig*8 + r
    const int dg = slot >> 2;                    // d = dg*8 + dd (4 ig of a wave share dg)
    const int d0 = dg * 8;
    const int pbase = tl * 32;

    const float* cx  = x  + (size_t)b * Cq * Tq + (size_t)(32 + d0) * Tq + t0 + tl;
    const float* cxi = xi + (size_t)b * Cq * Tq + (size_t)(32 + d0) * Tq + t0 + tl;

    float acc[8][8];
#pragma unroll
    for (int r = 0; r < 8; ++r)
#pragma unroll
        for (int dd = 0; dd < 8; ++dd) acc[r][dd] = 0.f;

    // issue k=0 ctx loads before the barrier (independent of LDS)
    float c0[8], c1[8];
#pragma unroll
    for (int dd = 0; dd < 8; ++dd) c0[dd] = cx[(size_t)dd * Tq];
#pragma unroll
    for (int dd = 0; dd < 8; ++dd) c1[dd] = cx[(size_t)(96 + dd) * Tq];

    __syncthreads();

    // j-pairs: k = 0..15 from x (j=2k,2k+1), k = 16..31 from xi
#pragma unroll 2
    for (int k = 0; k < 32; ++k) {
        const uint4 wa = *reinterpret_cast<const uint4*>(
            &plds[k * 512 + pbase + ((ig * 8 + 0) ^ xw)]);
        const uint4 wb = *reinterpret_cast<const uint4*>(
            &plds[k * 512 + pbase + ((ig * 8 + 4) ^ xw)]);
        float pj0[8], pj1[8];
        pj0[0] = __uint_as_float(wa.x << 16);  pj1[0] = __uint_as_float(wa.x & 0xffff0000u);
        pj0[1] = __uint_as_float(wa.y << 16);  pj1[1] = __uint_as_float(wa.y & 0xffff0000u);
        pj0[2] = __uint_as_float(wa.z << 16);  pj1[2] = __uint_as_float(wa.z & 0xffff0000u);
        pj0[3] = __uint_as_float(wa.w << 16);  pj1[3] = __uint_as_float(wa.w & 0xffff0000u);
        pj0[4] = __uint_as_float(wb.x << 16);  pj1[4] = __uint_as_float(wb.x & 0xffff0000u);
        pj0[5] = __uint_as_float(wb.y << 16);  pj1[5] = __uint_as_float(wb.y & 0xffff0000u);
        pj0[6] = __uint_as_float(wb.z << 16);  pj1[6] = __uint_as_float(wb.z & 0xffff0000u);
        pj0[7] = __uint_as_float(wb.w << 16);  pj1[7] = __uint_as_float(wb.w & 0xffff0000u);

        if (k > 0) {            // k=0 already loaded pre-barrier
            const float* base = (k < 16) ? cx : cxi;
            const int kg = k & 15;
#pragma unroll
            for (int dd = 0; dd < 8; ++dd)
                c0[dd] = base[(size_t)(kg * 192 + dd) * Tq];
#pragma unroll
            for (int dd = 0; dd < 8; ++dd)
                c1[dd] = base[(size_t)(kg * 192 + 96 + dd) * Tq];
        }

#pragma unroll
        for (int r = 0; r < 8; ++r)
#pragma unroll
            for (int dd = 0; dd < 8; ++dd)
                acc[r][dd] += pj0[r] * c0[dd] + pj1[r] * c1[dd];
    }

    float* ob = out + (size_t)b * 2048 * Tq + t0 + tl;
#pragma unroll
    for (int r = 0; r < 8; ++r)
#pragma unroll
        for (int dd = 0; dd < 8; ++dd) {
            int ch = (ig * 8 + r) * 64 + d0 + dd;
            __builtin_nontemporal_store(acc[r][dd], &ob[(size_t)ch * Tq]);
        }
}

extern "C" void kernel_launch(void* const* d_in, const int* in_sizes, int n_in,
                              void* d_out, int out_size, void* d_ws, size_t ws_size,
                              hipStream_t stream) {
    const float* x  = (const float*)d_in[0];
    const float* xi = (const float*)d_in[1];
    float* out = (float*)d_out;
    attn_v7<<<dim3(NBLK), dim3(512), 0, stream>>>(x, xi, out);
}

// Round 8
// 303.997 us; speedup vs baseline: 2.2360x; 1.2082x over previous
//
#include <hip/hip_runtime.h>

// SimpleAttention v8: v5 geometry frozen (TT=32, 1024 thr, 128KB p-LDS),
// inner product packed as f32x2 -> v_pk_fma_f32 (halves FMA issue cycles).
// out[b, i*64+d, t] = sum_j softmax_j(a[i][j]) * ctx[j][d]   (per b,t)
// attentions[b,i,j,t] = p[j] + (i==j ? 0 : p[j+32])

typedef unsigned int uint_t;
typedef float f32x2 __attribute__((ext_vector_type(2)));

constexpr int Bq = 16, Cq = 3072, Tq = 2048;
constexpr int TT = 32;                   // t-tile = one 128B line
constexpr int TILES = Tq / TT;           // 64
constexpr int NBLK = Bq * TILES;         // 1024
constexpr size_t ATT_OFF = (size_t)Bq * 2048 * Tq;

__global__ __launch_bounds__(1024, 4) void attn_v8(const float* __restrict__ x,
                                                   const float* __restrict__ xi,
                                                   float* __restrict__ out)
{
    // p packed bf16 pairs: word k holds (p[2k], p[2k+1]) for row i, time tl.
    // word-index = k*1024 + tl*32 + (i ^ ((tl&7)<<2))   -> 128 KB
    __shared__ uint_t plds[32 * 32 * 32];

    const int b    = (int)blockIdx.x >> 6;
    const int tile = (int)blockIdx.x & (TILES - 1);
    const int t0   = tile * TT;
    const int tl   = (int)threadIdx.x & 31;
    const int slot = (int)threadIdx.x >> 5;      // 0..31
    const int xw   = (tl & 7) << 2;              // word-index XOR swizzle

    const float* xb  = x  + (size_t)b * Cq * Tq + t0 + tl;
    const float* xib = xi + (size_t)b * Cq * Tq + t0 + tl;

    // ---- phase A: softmax for row i = slot; attn out; p -> LDS ----
    {
        const int i = slot;
        float p[64];
#pragma unroll
        for (int j = 0; j < 32; ++j) p[j]      = xb [(size_t)(i * 96 + j) * Tq];
#pragma unroll
        for (int j = 0; j < 32; ++j) p[j + 32] = xib[(size_t)(i * 96 + j) * Tq];
        float m = p[0];
#pragma unroll
        for (int j = 1; j < 64; ++j) m = fmaxf(m, p[j]);
        float s = 0.f;
#pragma unroll
        for (int j = 0; j < 64; ++j) { p[j] = __expf(p[j] - m); s += p[j]; }
        const float inv = 1.f / s;
#pragma unroll
        for (int j = 0; j < 64; ++j) p[j] *= inv;

        float* ao = out + ATT_OFF + ((size_t)(b * 32 + i) * 32) * Tq + t0 + tl;
#pragma unroll
        for (int j = 0; j < 32; ++j) {
            float v = p[j] + ((j == i) ? 0.f : p[j + 32]);
            __builtin_nontemporal_store(v, &ao[(size_t)j * Tq]);
        }
#pragma unroll
        for (int k = 0; k < 32; ++k) {
            uint_t b0 = __float_as_uint(p[2 * k]);
            uint_t b1 = __float_as_uint(p[2 * k + 1]);
            uint_t lo = (b0 + 0x7fffu + ((b0 >> 16) & 1u)) >> 16;
            uint_t hi = (b1 + 0x7fffu + ((b1 >> 16) & 1u)) >> 16;
            plds[k * 1024 + tl * 32 + (i ^ xw)] = lo | (hi << 16);
        }
    }
    __syncthreads();

    // ---- phase B: thread = (ig,dg,tl); acc 8i x 8d as f32x2 pairs ----
    const int ig = slot & 3;                     // i = ig*8 + r
    const int dg = slot >> 2;                    // d = dg*8 + dd
    const int d0 = dg * 8;
    const int pbase = tl * 32;

    const float* cx  = x  + (size_t)b * Cq * Tq + (size_t)(32 + d0) * Tq + t0 + tl;
    const float* cxi = xi + (size_t)b * Cq * Tq + (size_t)(32 + d0) * Tq + t0 + tl;

    f32x2 acc2[8][4];
#pragma unroll
    for (int r = 0; r < 8; ++r)
#pragma unroll
        for (int q = 0; q < 4; ++q) acc2[r][q] = (f32x2)(0.f);

    // j-pairs: k = 0..15 from x (j=2k,2k+1), k = 16..31 from xi
#pragma unroll 2
    for (int k = 0; k < 32; ++k) {
        const float* base = (k < 16) ? cx : cxi;
        const int kg = k & 15;                   // j' = 2*kg, 2*kg+1
        const uint4 wa = *reinterpret_cast<const uint4*>(
            &plds[k * 1024 + pbase + ((ig * 8 + 0) ^ xw)]);
        const uint4 wb = *reinterpret_cast<const uint4*>(
            &plds[k * 1024 + pbase + ((ig * 8 + 4) ^ xw)]);
        float pj0[8], pj1[8];
        pj0[0] = __uint_as_float(wa.x << 16);  pj1[0] = __uint_as_float(wa.x & 0xffff0000u);
        pj0[1] = __uint_as_float(wa.y << 16);  pj1[1] = __uint_as_float(wa.y & 0xffff0000u);
        pj0[2] = __uint_as_float(wa.z << 16);  pj1[2] = __uint_as_float(wa.z & 0xffff0000u);
        pj0[3] = __uint_as_float(wa.w << 16);  pj1[3] = __uint_as_float(wa.w & 0xffff0000u);
        pj0[4] = __uint_as_float(wb.x << 16);  pj1[4] = __uint_as_float(wb.x & 0xffff0000u);
        pj0[5] = __uint_as_float(wb.y << 16);  pj1[5] = __uint_as_float(wb.y & 0xffff0000u);
        pj0[6] = __uint_as_float(wb.z << 16);  pj1[6] = __uint_as_float(wb.z & 0xffff0000u);
        pj0[7] = __uint_as_float(wb.w << 16);  pj1[7] = __uint_as_float(wb.w & 0xffff0000u);

        f32x2 c0p[4], c1p[4];
#pragma unroll
        for (int q = 0; q < 4; ++q) {
            c0p[q].x = base[(size_t)(kg * 192 + 2 * q) * Tq];
            c0p[q].y = base[(size_t)(kg * 192 + 2 * q + 1) * Tq];
        }
#pragma unroll
        for (int q = 0; q < 4; ++q) {
            c1p[q].x = base[(size_t)(kg * 192 + 96 + 2 * q) * Tq];
            c1p[q].y = base[(size_t)(kg * 192 + 96 + 2 * q + 1) * Tq];
        }

#pragma unroll
        for (int r = 0; r < 8; ++r) {
            const f32x2 pb0 = (f32x2)(pj0[r]);
            const f32x2 pb1 = (f32x2)(pj1[r]);
#pragma unroll
            for (int q = 0; q < 4; ++q)
                acc2[r][q] += pb0 * c0p[q] + pb1 * c1p[q];
        }
    }

    float* ob = out + (size_t)b * 2048 * Tq + t0 + tl;
#pragma unroll
    for (int r = 0; r < 8; ++r)
#pragma unroll
        for (int q = 0; q < 4; ++q) {
            int ch = (ig * 8 + r) * 64 + d0 + 2 * q;
            __builtin_nontemporal_store(acc2[r][q].x, &ob[(size_t)ch * Tq]);
            __builtin_nontemporal_store(acc2[r][q].y, &ob[(size_t)(ch + 1) * Tq]);
        }
}

extern "C" void kernel_launch(void* const* d_in, const int* in_sizes, int n_in,
                              void* d_out, int out_size, void* d_ws, size_t ws_size,
                              hipStream_t stream) {
    const float* x  = (const float*)d_in[0];
    const float* xi = (const float*)d_in[1];
    float* out = (float*)d_out;
    attn_v8<<<dim3(NBLK), dim3(1024), 0, stream>>>(x, xi, out);
}